// Round 1
// baseline (3491.246 us; speedup 1.0000x reference)
//
#include <hip/hip_runtime.h>

#define H_ 300
#define B_ 1024
#define LMAX_ 64
#define N_ 49152
#define GST (19 * 20 * 512)  // ushorts per gate block in repacked weights

typedef __attribute__((ext_vector_type(8))) short short8;
typedef __attribute__((ext_vector_type(4))) float f32x4;

__device__ __forceinline__ unsigned short f2bf(float f) {
  unsigned int u = __float_as_uint(f);
  u += 0x7FFFu + ((u >> 16) & 1u);
  return (unsigned short)(u >> 16);
}

// ---------- segment start/len from (batch, pos) ----------
__global__ void seg_kernel(const int* __restrict__ batch, const int* __restrict__ pos,
                           int* __restrict__ seg_start, int* __restrict__ seg_len) {
  int i = blockIdx.x * blockDim.x + threadIdx.x;
  if (i >= N_) return;
  int b = batch[i], p = pos[i];
  if (p == 0) seg_start[b] = i;
  if (i == N_ - 1 || batch[i + 1] != b) seg_len[b] = p + 1;
}

// ---------- repack weights into B-fragment order, bf16 ----------
// WB[dir][gate][ct][kt][lane][i]; k_g = kt*32+(lane>>4)*8+i (merged K=640:
// k<320 -> w_ih[k], k>=320 -> w_hh[k-320]); col = ct*16+(lane&15); j = gate*300+col
__global__ void wb_kernel(const float* __restrict__ w_ih_f, const float* __restrict__ w_hh_f,
                          const float* __restrict__ w_ih_b, const float* __restrict__ w_hh_b,
                          unsigned short* __restrict__ wb) {
  int f = blockIdx.x * blockDim.x + threadIdx.x;  // < 2*3*19*20*512 = 1,167,360
  int i = f & 7;
  int l = (f >> 3) & 63;
  int rest = f >> 9;
  int kt = rest % 20; rest /= 20;
  int ct = rest % 19; rest /= 19;
  int gate = rest % 3;
  int dir = rest / 3;
  int kg = kt * 32 + ((l >> 4) << 3) + i;
  int col = ct * 16 + (l & 15);
  float v = 0.f;
  if (col < 300) {
    int j = gate * 300 + col;
    if (kg < 320) {
      if (kg < 300) v = (dir ? w_ih_b : w_ih_f)[j * 300 + kg];
    } else {
      int k2 = kg - 320;
      if (k2 < 300) v = (dir ? w_hh_b : w_hh_f)[j * 300 + k2];
    }
  }
  wb[f] = f2bf(v);
}

// ---------- h0 = segment max ----------
__global__ void h0_kernel(const float* __restrict__ node, const int* __restrict__ seg_start,
                          const int* __restrict__ seg_len, float* __restrict__ h0) {
  int g = blockIdx.x;
  int col = threadIdx.x;
  if (col >= H_) return;
  int s0 = seg_start[g], L = seg_len[g];
  const float* p = node + (size_t)s0 * H_ + col;
  float m = p[0];
  for (int r = 1; r < L; ++r) m = fmaxf(m, p[(size_t)r * H_]);
  h0[g * H_ + col] = m;
}

// ---------- fused bidirectional GRU, MFMA ----------
__global__ __launch_bounds__(1024) void gru_kernel(
    const float* __restrict__ node, const float* __restrict__ biasv,
    const float* __restrict__ b_ih_f, const float* __restrict__ b_hh_f,
    const float* __restrict__ b_ih_b, const float* __restrict__ b_hh_b,
    const unsigned short* __restrict__ wb, const float* __restrict__ h0,
    const int* __restrict__ seg_start, const int* __restrict__ seg_len,
    float* __restrict__ out) {
  __shared__ unsigned short XS[32 * 336];      // x_t, bf16, K-padded to 336
  __shared__ unsigned short HBF[2][32 * 336];  // bf16 mirror of h, double-buffered
  __shared__ float HS[32 * 304];               // fp32 master h
  __shared__ float BI[912], BH[912], BB[304];
  __shared__ int SST[32], SLN[32], SGG[32];

  int tid = threadIdx.x;
  int blk = blockIdx.x;
  int dir = blk >> 5;   // 0..31 fwd, 32..63 bwd
  int db = blk & 31;

  if (tid < 32) {
    int s = tid;
    // parity grouping: even graphs (len 32) together so fwd blocks can stop early
    int g = (db < 16) ? 2 * (db * 32 + s) : 2 * ((db - 16) * 32 + s) + 1;
    SGG[s] = g;
    SST[s] = seg_start[g];
    SLN[s] = seg_len[g];
  }
  const float* bip = dir ? b_ih_b : b_ih_f;
  const float* bhp = dir ? b_hh_b : b_hh_f;
  for (int idx = tid; idx < 912; idx += 1024) {
    BI[idx] = idx < 900 ? bip[idx] : 0.f;
    BH[idx] = idx < 900 ? bhp[idx] : 0.f;
  }
  for (int idx = tid; idx < 75; idx += 1024)
    *(float4*)&BB[idx * 4] = *(const float4*)&biasv[idx * 4];
  __syncthreads();

  // init h from h0 (fp32 + bf16 mirror buf0; zero buf1)
  for (int idx = tid; idx < 32 * 84; idx += 1024) {
    int s = idx / 84, c4 = idx - s * 84;
    float4 v = {0.f, 0.f, 0.f, 0.f};
    if (c4 < 75) v = *(const float4*)(h0 + (size_t)SGG[s] * 300 + c4 * 4);
    if (c4 < 76) *(float4*)&HS[s * 304 + c4 * 4] = v;
    uint2 pk;
    pk.x = (unsigned)f2bf(v.x) | ((unsigned)f2bf(v.y) << 16);
    pk.y = (unsigned)f2bf(v.z) | ((unsigned)f2bf(v.w) << 16);
    *(uint2*)&HBF[0][s * 336 + c4 * 4] = pk;
    uint2 z2 = {0u, 0u};
    *(uint2*)&HBF[1][s * 336 + c4 * 4] = z2;
  }

  int nsteps = 64;
  if (dir == 0) {
    int m = 0;
    for (int s = 0; s < 32; ++s) m = max(m, SLN[s]);
    nsteps = m;
  }

  int lane = tid & 63;
  int wave = tid >> 6;
  const unsigned short* wbd = wb + (size_t)dir * 3 * GST;
  int arow0 = (lane & 15) * 336 + ((lane >> 4) << 3);

  for (int t = 0; t < nsteps; ++t) {
    int tt = dir ? (63 - t) : t;
    int rb = t & 1, wbuf = rb ^ 1;

    // stage x_t = relu(node_row + bias), bf16, zeros at padding
    for (int idx = tid; idx < 32 * 84; idx += 1024) {
      int s = idx / 84, c4 = idx - s * 84;
      uint2 pk = {0u, 0u};
      if (c4 < 75 && tt < SLN[s]) {
        float4 v = *(const float4*)(node + (size_t)(SST[s] + tt) * 300 + c4 * 4);
        float4 bv = *(const float4*)&BB[c4 * 4];
        float a0 = fmaxf(v.x + bv.x, 0.f), a1 = fmaxf(v.y + bv.y, 0.f);
        float a2 = fmaxf(v.z + bv.z, 0.f), a3 = fmaxf(v.w + bv.w, 0.f);
        pk.x = (unsigned)f2bf(a0) | ((unsigned)f2bf(a1) << 16);
        pk.y = (unsigned)f2bf(a2) | ((unsigned)f2bf(a3) << 16);
      }
      *(uint2*)&XS[s * 336 + c4 * 4] = pk;
    }
    __syncthreads();

    for (int ct = wave; ct < 19; ct += 16) {
      f32x4 ar0 = {0,0,0,0}, ar1 = {0,0,0,0}, az0 = {0,0,0,0}, az1 = {0,0,0,0};
      f32x4 ani0 = {0,0,0,0}, ani1 = {0,0,0,0}, anh0 = {0,0,0,0}, anh1 = {0,0,0,0};
      const unsigned short* wct = wbd + ct * (20 * 512) + lane * 8;

      // K-half 1: X @ W_ih (r,z accumulate merged; n -> ani)
      #pragma unroll
      for (int kt = 0; kt < 10; ++kt) {
        short8 a0 = *(const short8*)&XS[arow0 + kt * 32];
        short8 a1 = *(const short8*)&XS[arow0 + 16 * 336 + kt * 32];
        short8 br = *(const short8*)(wct + kt * 512);
        short8 bz = *(const short8*)(wct + GST + kt * 512);
        short8 bn = *(const short8*)(wct + 2 * GST + kt * 512);
        ar0 = __builtin_amdgcn_mfma_f32_16x16x32_bf16(a0, br, ar0, 0, 0, 0);
        ar1 = __builtin_amdgcn_mfma_f32_16x16x32_bf16(a1, br, ar1, 0, 0, 0);
        az0 = __builtin_amdgcn_mfma_f32_16x16x32_bf16(a0, bz, az0, 0, 0, 0);
        az1 = __builtin_amdgcn_mfma_f32_16x16x32_bf16(a1, bz, az1, 0, 0, 0);
        ani0 = __builtin_amdgcn_mfma_f32_16x16x32_bf16(a0, bn, ani0, 0, 0, 0);
        ani1 = __builtin_amdgcn_mfma_f32_16x16x32_bf16(a1, bn, ani1, 0, 0, 0);
      }
      // K-half 2: H @ W_hh (r,z continue merged; n -> anh)
      const unsigned short* hb = HBF[rb];
      #pragma unroll
      for (int kt = 0; kt < 10; ++kt) {
        short8 a0 = *(const short8*)&hb[arow0 + kt * 32];
        short8 a1 = *(const short8*)&hb[arow0 + 16 * 336 + kt * 32];
        short8 br = *(const short8*)(wct + (10 + kt) * 512);
        short8 bz = *(const short8*)(wct + GST + (10 + kt) * 512);
        short8 bn = *(const short8*)(wct + 2 * GST + (10 + kt) * 512);
        ar0 = __builtin_amdgcn_mfma_f32_16x16x32_bf16(a0, br, ar0, 0, 0, 0);
        ar1 = __builtin_amdgcn_mfma_f32_16x16x32_bf16(a1, br, ar1, 0, 0, 0);
        az0 = __builtin_amdgcn_mfma_f32_16x16x32_bf16(a0, bz, az0, 0, 0, 0);
        az1 = __builtin_amdgcn_mfma_f32_16x16x32_bf16(a1, bz, az1, 0, 0, 0);
        anh0 = __builtin_amdgcn_mfma_f32_16x16x32_bf16(a0, bn, anh0, 0, 0, 0);
        anh1 = __builtin_amdgcn_mfma_f32_16x16x32_bf16(a1, bn, anh1, 0, 0, 0);
      }

      // gates + h update (each (s,col) owned by exactly one lane)
      int col = ct * 16 + (lane & 15);
      float bir = BI[col] + BH[col];
      float biz = BI[300 + col] + BH[300 + col];
      float bin = BI[600 + col];
      float bhn = BH[600 + col];
      int r0 = (lane >> 4) << 2;
      #pragma unroll
      for (int mt = 0; mt < 2; ++mt) {
        f32x4 ar = mt ? ar1 : ar0;
        f32x4 az = mt ? az1 : az0;
        f32x4 ani = mt ? ani1 : ani0;
        f32x4 anh = mt ? anh1 : anh0;
        #pragma unroll
        for (int i = 0; i < 4; ++i) {
          int s = mt * 16 + r0 + i;
          float pr = ar[i] + bir;
          float pz = az[i] + biz;
          float rr = 1.f / (1.f + __expf(-pr));
          float zz = 1.f / (1.f + __expf(-pz));
          float pn = (ani[i] + bin) + rr * (anh[i] + bhn);
          float nn = 1.f - 2.f / (__expf(2.f * pn) + 1.f);
          float ho = HS[s * 304 + col];
          float hn = fmaf(zz, ho - nn, nn);  // (1-z)*n + z*h
          HS[s * 304 + col] = hn;
          HBF[wbuf][s * 336 + col] = f2bf(hn);
          if (col < 300 && tt < SLN[s])
            out[(size_t)(SST[s] + tt) * 600 + dir * 300 + col] = hn;
        }
      }
    }
    __syncthreads();
  }
}

extern "C" void kernel_launch(void* const* d_in, const int* in_sizes, int n_in,
                              void* d_out, int out_size, void* d_ws, size_t ws_size,
                              hipStream_t stream) {
  const float* node   = (const float*)d_in[0];
  const int*   batch  = (const int*)d_in[1];
  const int*   pos    = (const int*)d_in[2];
  const float* bias   = (const float*)d_in[3];
  const float* w_ih_f = (const float*)d_in[4];
  const float* w_hh_f = (const float*)d_in[5];
  const float* b_ih_f = (const float*)d_in[6];
  const float* b_hh_f = (const float*)d_in[7];
  const float* w_ih_b = (const float*)d_in[8];
  const float* w_hh_b = (const float*)d_in[9];
  const float* b_ih_b = (const float*)d_in[10];
  const float* b_hh_b = (const float*)d_in[11];
  float* outp = (float*)d_out;

  // ws layout: wb (2,334,720 B) | h0 (1,228,800 B) | seg_start (4KB) | seg_len (4KB)
  unsigned short* wb = (unsigned short*)d_ws;
  float* h0 = (float*)((char*)d_ws + 2334720);
  int* seg_start = (int*)((char*)d_ws + 2334720 + 1228800);
  int* seg_len = seg_start + 1024;

  seg_kernel<<<(N_ + 255) / 256, 256, 0, stream>>>(batch, pos, seg_start, seg_len);
  wb_kernel<<<4560, 256, 0, stream>>>(w_ih_f, w_hh_f, w_ih_b, w_hh_b, wb);
  h0_kernel<<<B_, 320, 0, stream>>>(node, seg_start, seg_len, h0);
  gru_kernel<<<64, 1024, 0, stream>>>(node, bias, b_ih_f, b_hh_f, b_ih_b, b_hh_b,
                                      wb, h0, seg_start, seg_len, outp);
}

// Round 2
// 3106.125 us; speedup vs baseline: 1.1240x; 1.1240x over previous
//
#include <hip/hip_runtime.h>

#define H_ 300
#define B_ 1024
#define N_ 49152
#define GST (19 * 20 * 512)  // ushorts per gate block in repacked weights
#define XSTR 344             // ushort stride for XS/HBF rows (bank-conflict-free b128)
#define HSTR 304

typedef __attribute__((ext_vector_type(8))) short short8;
typedef __attribute__((ext_vector_type(4))) float f32x4;

__device__ __forceinline__ unsigned short f2bf(float f) {
  unsigned int u = __float_as_uint(f);
  u += 0x7FFFu + ((u >> 16) & 1u);
  return (unsigned short)(u >> 16);
}
__device__ __forceinline__ unsigned pack2bf(float a, float b) {
  return (unsigned)f2bf(a) | ((unsigned)f2bf(b) << 16);
}

// ---------- segment start/len from (batch, pos) ----------
__global__ void seg_kernel(const int* __restrict__ batch, const int* __restrict__ pos,
                           int* __restrict__ seg_start, int* __restrict__ seg_len) {
  int i = blockIdx.x * blockDim.x + threadIdx.x;
  if (i >= N_) return;
  int b = batch[i], p = pos[i];
  if (p == 0) seg_start[b] = i;
  if (i == N_ - 1 || batch[i + 1] != b) seg_len[b] = p + 1;
}

// ---------- repack weights into B-fragment order, bf16 ----------
// WB[dir][gate][ct][kt][lane][i]; k_g = kt*32+(lane>>4)*8+i (merged K=640:
// k<320 -> w_ih[k], k>=320 -> w_hh[k-320]); col = ct*16+(lane&15); j = gate*300+col
__global__ void wb_kernel(const float* __restrict__ w_ih_f, const float* __restrict__ w_hh_f,
                          const float* __restrict__ w_ih_b, const float* __restrict__ w_hh_b,
                          unsigned short* __restrict__ wb) {
  int f = blockIdx.x * blockDim.x + threadIdx.x;  // < 2*3*19*20*512 = 1,167,360
  int i = f & 7;
  int l = (f >> 3) & 63;
  int rest = f >> 9;
  int kt = rest % 20; rest /= 20;
  int ct = rest % 19; rest /= 19;
  int gate = rest % 3;
  int dir = rest / 3;
  int kg = kt * 32 + ((l >> 4) << 3) + i;
  int col = ct * 16 + (l & 15);
  float v = 0.f;
  if (col < 300) {
    int j = gate * 300 + col;
    if (kg < 320) {
      if (kg < 300) v = (dir ? w_ih_b : w_ih_f)[j * 300 + kg];
    } else {
      int k2 = kg - 320;
      if (k2 < 300) v = (dir ? w_hh_b : w_hh_f)[j * 300 + k2];
    }
  }
  wb[f] = f2bf(v);
}

// ---------- h0 = segment max (4-way unrolled row loop) ----------
__global__ void h0_kernel(const float* __restrict__ node, const int* __restrict__ seg_start,
                          const int* __restrict__ seg_len, float* __restrict__ h0) {
  int g = blockIdx.x;
  int col = threadIdx.x;
  if (col >= H_) return;
  int s0 = seg_start[g], L = seg_len[g];
  const float* p = node + (size_t)s0 * H_ + col;
  float ma = p[0], mb = -3.4e38f, mc = -3.4e38f, md = -3.4e38f;
  int r = 1;
  for (; r + 3 < L; r += 4) {
    ma = fmaxf(ma, p[(size_t)r * H_]);
    mb = fmaxf(mb, p[(size_t)(r + 1) * H_]);
    mc = fmaxf(mc, p[(size_t)(r + 2) * H_]);
    md = fmaxf(md, p[(size_t)(r + 3) * H_]);
  }
  for (; r < L; ++r) ma = fmaxf(ma, p[(size_t)r * H_]);
  h0[g * H_ + col] = fmaxf(fmaxf(ma, mb), fmaxf(mc, md));
}

// ---------- fused bidirectional GRU, weight-stationary MFMA ----------
// 128 blocks x 1024 thr. Block = 16 sequences of one direction.
// Wave w holds full merged B (K=640) for column-triplet tile w in registers.
// Tiles 16..18 are K-split: ih-half -> waves 0..2, hh-half -> waves 4..6,
// partials combined through PS in LDS.
__global__ __launch_bounds__(1024, 4) void gru_kernel(
    const float* __restrict__ node, const float* __restrict__ biasv,
    const float* __restrict__ b_ih_f, const float* __restrict__ b_hh_f,
    const float* __restrict__ b_ih_b, const float* __restrict__ b_hh_b,
    const unsigned short* __restrict__ wb, const float* __restrict__ h0,
    const int* __restrict__ seg_start, const int* __restrict__ seg_len,
    float* __restrict__ out) {
  __shared__ unsigned short XS[16 * XSTR];      // x_t bf16
  __shared__ unsigned short HBF[2][16 * XSTR];  // bf16 h mirror, double-buffered
  __shared__ float HS[16 * HSTR];               // fp32 master h
  __shared__ float PS[3][3][256];               // split-tile partials (r,z,n-ih)
  __shared__ float BI[912], BH[912], BB[304];
  __shared__ int SST[16], SLN[16], SGG[16];

  int tid = threadIdx.x;
  int blk = blockIdx.x;
  int dir = blk >> 6;
  int db = blk & 63;

  if (tid < 16) {
    int g = (db < 32) ? 2 * (db * 16 + tid) : 2 * ((db - 32) * 16 + tid) + 1;
    SGG[tid] = g;
    SST[tid] = seg_start[g];
    SLN[tid] = seg_len[g];
  }
  const float* bip = dir ? b_ih_b : b_ih_f;
  const float* bhp = dir ? b_hh_b : b_hh_f;
  for (int i = tid; i < 912; i += 1024) {
    BI[i] = i < 900 ? bip[i] : 0.f;
    BH[i] = i < 900 ? bhp[i] : 0.f;
  }
  for (int i = tid; i < 76; i += 1024) {
    float4 v = {0.f, 0.f, 0.f, 0.f};
    if (i < 75) v = *(const float4*)(biasv + i * 4);
    *(float4*)&BB[i * 4] = v;
  }
  __syncthreads();

  // init HS + HBF[0] from h0; zero pad tails of XS/HBF
  for (int idx = tid; idx < 16 * 76; idx += 1024) {
    int s = idx / 76, c4 = idx - s * 76;
    float4 v = {0.f, 0.f, 0.f, 0.f};
    if (c4 < 75) v = *(const float4*)(h0 + (size_t)SGG[s] * 300 + c4 * 4);
    *(float4*)&HS[s * HSTR + c4 * 4] = v;
    uint2 pk;
    pk.x = pack2bf(v.x, v.y);
    pk.y = pack2bf(v.z, v.w);
    *(uint2*)&HBF[0][s * XSTR + c4 * 4] = pk;
  }
  for (int idx = tid; idx < 16 * 11; idx += 1024) {
    int s = idx / 11, c4 = 75 + (idx - s * 11);  // c4 in 75..85
    uint2 z = {0u, 0u};
    if (c4 >= 76) *(uint2*)&HBF[0][s * XSTR + c4 * 4] = z;
    *(uint2*)&HBF[1][s * XSTR + c4 * 4] = z;
    *(uint2*)&XS[s * XSTR + c4 * 4] = z;
  }

  int lane = tid & 63, wave = tid >> 6;
  const unsigned short* wbd = wb + (size_t)dir * 3 * GST;
  const unsigned short* wct = wbd + wave * (20 * 512) + lane * 8;

  // ---- weight-stationary preload: full tile per wave ----
  short8 WR[20], WZ[20], WN[20];
  #pragma unroll
  for (int kt = 0; kt < 20; ++kt) {
    WR[kt] = *(const short8*)(wct + kt * 512);
    WZ[kt] = *(const short8*)(wct + GST + kt * 512);
    WN[kt] = *(const short8*)(wct + 2 * GST + kt * 512);
  }
  // split tiles: role 1 = ih-half of tile 16+wave (waves 0..2),
  //              role 2 = hh-half of tile 12+wave (waves 4..6, owner)
  int role = (wave < 3) ? 1 : ((wave >= 4 && wave < 7) ? 2 : 0);
  int ct2 = (role == 1) ? (16 + wave) : (12 + wave);
  short8 ER[10], EZ[10], EN[10];
  if (role) {
    const unsigned short* w2 = wbd + ct2 * (20 * 512) + lane * 8 + (role == 2 ? 10 * 512 : 0);
    #pragma unroll
    for (int j = 0; j < 10; ++j) {
      ER[j] = *(const short8*)(w2 + j * 512);
      EZ[j] = *(const short8*)(w2 + GST + j * 512);
      EN[j] = *(const short8*)(w2 + 2 * GST + j * 512);
    }
  }

  // hoisted per-wave gate constants
  int colF = wave * 16 + (lane & 15);
  int s0w = (lane >> 4) * 4;
  float birF = BI[colF] + BH[colF];
  float bizF = BI[300 + colF] + BH[300 + colF];
  float binF = BI[600 + colF];
  float bhnF = BH[600 + colF];
  int col2 = ct2 * 16 + (lane & 15);
  float bir2 = 0.f, biz2 = 0.f, bin2 = 0.f, bhn2 = 0.f;
  if (role == 2) {
    bir2 = BI[col2] + BH[col2];
    biz2 = BI[300 + col2] + BH[300 + col2];
    bin2 = BI[600 + col2];
    bhn2 = BH[600 + col2];
  }

  int nsteps = 64;
  if (dir == 0) {
    int m = 0;
    for (int s = 0; s < 16; ++s) m = max(m, SLN[s]);
    nsteps = m;
  }

  // prefetch lane constants: 1200 float4 slots (16 rows x 75)
  int sa = tid / 75, ca = tid - sa * 75;
  bool va = tid < 1200;
  int tb2 = tid + 1024;
  int sb = tb2 / 75, cb = tb2 - sb * 75;
  bool vb = tb2 < 1200;

  // stage x(t=0)
  {
    int tt0 = dir ? 63 : 0;
    if (va) {
      float4 p = {0.f, 0.f, 0.f, 0.f};
      bool rv = tt0 < SLN[sa];
      if (rv) p = *(const float4*)(node + (size_t)(SST[sa] + tt0) * 300 + ca * 4);
      float4 bv = *(const float4*)&BB[ca * 4];
      uint2 pk = {0u, 0u};
      if (rv) {
        pk.x = pack2bf(fmaxf(p.x + bv.x, 0.f), fmaxf(p.y + bv.y, 0.f));
        pk.y = pack2bf(fmaxf(p.z + bv.z, 0.f), fmaxf(p.w + bv.w, 0.f));
      }
      *(uint2*)&XS[sa * XSTR + ca * 4] = pk;
    }
    if (vb) {
      float4 p = {0.f, 0.f, 0.f, 0.f};
      bool rv = tt0 < SLN[sb];
      if (rv) p = *(const float4*)(node + (size_t)(SST[sb] + tt0) * 300 + cb * 4);
      float4 bv = *(const float4*)&BB[cb * 4];
      uint2 pk = {0u, 0u};
      if (rv) {
        pk.x = pack2bf(fmaxf(p.x + bv.x, 0.f), fmaxf(p.y + bv.y, 0.f));
        pk.y = pack2bf(fmaxf(p.z + bv.z, 0.f), fmaxf(p.w + bv.w, 0.f));
      }
      *(uint2*)&XS[sb * XSTR + cb * 4] = pk;
    }
  }
  __syncthreads();

  int arow0 = (lane & 15) * XSTR + ((lane >> 4) << 3);

  for (int t = 0; t < nsteps; ++t) {
    int tt = dir ? 63 - t : t;
    int rb = t & 1, wbf = rb ^ 1;
    bool havePf = (t + 1) < nsteps;
    int tt1 = dir ? 62 - t : t + 1;

    // issue prefetch of x(t+1) (in flight during MFMA)
    float4 pa = {0.f, 0.f, 0.f, 0.f}, pb = {0.f, 0.f, 0.f, 0.f};
    bool rva = false, rvb = false;
    if (havePf && va && tt1 < SLN[sa]) {
      rva = true;
      pa = *(const float4*)(node + (size_t)(SST[sa] + tt1) * 300 + ca * 4);
    }
    if (havePf && vb && tt1 < SLN[sb]) {
      rvb = true;
      pb = *(const float4*)(node + (size_t)(SST[sb] + tt1) * 300 + cb * 4);
    }

    // ---- MFMA: base tile (branch-free), then split-half extras ----
    f32x4 ar = {0,0,0,0}, az = {0,0,0,0}, ani = {0,0,0,0}, anh = {0,0,0,0};
    f32x4 er = {0,0,0,0}, ez = {0,0,0,0}, en = {0,0,0,0};
    const unsigned short* hb = &HBF[rb][0];
    #pragma unroll
    for (int kt = 0; kt < 10; ++kt) {
      short8 a = *(const short8*)&XS[arow0 + kt * 32];
      ar = __builtin_amdgcn_mfma_f32_16x16x32_bf16(a, WR[kt], ar, 0, 0, 0);
      az = __builtin_amdgcn_mfma_f32_16x16x32_bf16(a, WZ[kt], az, 0, 0, 0);
      ani = __builtin_amdgcn_mfma_f32_16x16x32_bf16(a, WN[kt], ani, 0, 0, 0);
    }
    #pragma unroll
    for (int kt = 0; kt < 10; ++kt) {
      short8 a = *(const short8*)&hb[arow0 + kt * 32];
      ar = __builtin_amdgcn_mfma_f32_16x16x32_bf16(a, WR[10 + kt], ar, 0, 0, 0);
      az = __builtin_amdgcn_mfma_f32_16x16x32_bf16(a, WZ[10 + kt], az, 0, 0, 0);
      anh = __builtin_amdgcn_mfma_f32_16x16x32_bf16(a, WN[10 + kt], anh, 0, 0, 0);
    }
    if (role == 1) {
      #pragma unroll
      for (int kt = 0; kt < 10; ++kt) {
        short8 a = *(const short8*)&XS[arow0 + kt * 32];
        er = __builtin_amdgcn_mfma_f32_16x16x32_bf16(a, ER[kt], er, 0, 0, 0);
        ez = __builtin_amdgcn_mfma_f32_16x16x32_bf16(a, EZ[kt], ez, 0, 0, 0);
        en = __builtin_amdgcn_mfma_f32_16x16x32_bf16(a, EN[kt], en, 0, 0, 0);
      }
      #pragma unroll
      for (int i = 0; i < 4; ++i) {
        int e = (s0w + i) * 16 + (lane & 15);
        PS[wave][0][e] = er[i];
        PS[wave][1][e] = ez[i];
        PS[wave][2][e] = en[i];
      }
    } else if (role == 2) {
      #pragma unroll
      for (int kt = 0; kt < 10; ++kt) {
        short8 a = *(const short8*)&hb[arow0 + kt * 32];
        er = __builtin_amdgcn_mfma_f32_16x16x32_bf16(a, ER[kt], er, 0, 0, 0);
        ez = __builtin_amdgcn_mfma_f32_16x16x32_bf16(a, EZ[kt], ez, 0, 0, 0);
        en = __builtin_amdgcn_mfma_f32_16x16x32_bf16(a, EN[kt], en, 0, 0, 0);
      }
    }

    // ---- gates + h update for own full tile ----
    #pragma unroll
    for (int i = 0; i < 4; ++i) {
      int s = s0w + i;
      float pr = ar[i] + birF;
      float pz = az[i] + bizF;
      float rr = 1.f / (1.f + __expf(-pr));
      float zz = 1.f / (1.f + __expf(-pz));
      float pn = (ani[i] + binF) + rr * (anh[i] + bhnF);
      float nn = 1.f - 2.f / (__expf(2.f * pn) + 1.f);
      float ho = HS[s * HSTR + colF];
      float hn = fmaf(zz, ho - nn, nn);
      HS[s * HSTR + colF] = hn;
      HBF[wbf][s * XSTR + colF] = f2bf(hn);
      if (tt < SLN[s]) out[(size_t)(SST[s] + tt) * 600 + dir * 300 + colF] = hn;
    }
    __syncthreads();  // partials visible; all done reading XS(t)/HBF[rb]

    // ---- split-tile owners combine + finish ----
    if (role == 2) {
      int w3 = wave - 4;
      #pragma unroll
      for (int i = 0; i < 4; ++i) {
        int s = s0w + i;
        int e = s * 16 + (lane & 15);
        float pr = er[i] + PS[w3][0][e] + bir2;
        float pz = ez[i] + PS[w3][1][e] + biz2;
        float rr = 1.f / (1.f + __expf(-pr));
        float zz = 1.f / (1.f + __expf(-pz));
        float pn = (PS[w3][2][e] + bin2) + rr * (en[i] + bhn2);
        float nn = 1.f - 2.f / (__expf(2.f * pn) + 1.f);
        float ho = HS[s * HSTR + col2];
        float hn = fmaf(zz, ho - nn, nn);
        HS[s * HSTR + col2] = hn;
        HBF[wbf][s * XSTR + col2] = f2bf(hn);
        if (col2 < 300 && tt < SLN[s])
          out[(size_t)(SST[s] + tt) * 600 + dir * 300 + col2] = hn;
      }
    }
    // ---- write prefetched x(t+1) into XS ----
    if (havePf) {
      if (va) {
        float4 bv = *(const float4*)&BB[ca * 4];
        uint2 pk = {0u, 0u};
        if (rva) {
          pk.x = pack2bf(fmaxf(pa.x + bv.x, 0.f), fmaxf(pa.y + bv.y, 0.f));
          pk.y = pack2bf(fmaxf(pa.z + bv.z, 0.f), fmaxf(pa.w + bv.w, 0.f));
        }
        *(uint2*)&XS[sa * XSTR + ca * 4] = pk;
      }
      if (vb) {
        float4 bv = *(const float4*)&BB[cb * 4];
        uint2 pk = {0u, 0u};
        if (rvb) {
          pk.x = pack2bf(fmaxf(pb.x + bv.x, 0.f), fmaxf(pb.y + bv.y, 0.f));
          pk.y = pack2bf(fmaxf(pb.z + bv.z, 0.f), fmaxf(pb.w + bv.w, 0.f));
        }
        *(uint2*)&XS[sb * XSTR + cb * 4] = pk;
      }
    }
    __syncthreads();  // XS(t+1) + HBF[wbf] complete
  }
}

extern "C" void kernel_launch(void* const* d_in, const int* in_sizes, int n_in,
                              void* d_out, int out_size, void* d_ws, size_t ws_size,
                              hipStream_t stream) {
  const float* node   = (const float*)d_in[0];
  const int*   batch  = (const int*)d_in[1];
  const int*   pos    = (const int*)d_in[2];
  const float* bias   = (const float*)d_in[3];
  const float* w_ih_f = (const float*)d_in[4];
  const float* w_hh_f = (const float*)d_in[5];
  const float* b_ih_f = (const float*)d_in[6];
  const float* b_hh_f = (const float*)d_in[7];
  const float* w_ih_b = (const float*)d_in[8];
  const float* w_hh_b = (const float*)d_in[9];
  const float* b_ih_b = (const float*)d_in[10];
  const float* b_hh_b = (const float*)d_in[11];
  float* outp = (float*)d_out;

  // ws layout: wb (2,334,720 B) | h0 (1,228,800 B) | seg_start | seg_len
  unsigned short* wb = (unsigned short*)d_ws;
  float* h0 = (float*)((char*)d_ws + 2334720);
  int* seg_start = (int*)((char*)d_ws + 2334720 + 1228800);
  int* seg_len = seg_start + 1024;

  seg_kernel<<<(N_ + 255) / 256, 256, 0, stream>>>(batch, pos, seg_start, seg_len);
  wb_kernel<<<4560, 256, 0, stream>>>(w_ih_f, w_hh_f, w_ih_b, w_hh_b, wb);
  h0_kernel<<<B_, 320, 0, stream>>>(node, seg_start, seg_len, h0);
  gru_kernel<<<128, 1024, 0, stream>>>(node, bias, b_ih_f, b_hh_f, b_ih_b, b_hh_b,
                                       wb, h0, seg_start, seg_len, outp);
}

// Round 3
// 1258.158 us; speedup vs baseline: 2.7749x; 2.4688x over previous
//
#include <hip/hip_runtime.h>

#define H_ 300
#define B_ 1024
#define N_ 49152
#define XSTR 328   // ushort stride for 16-row bf16 tiles (2-way-max bank aliasing)
#define HSTR 304

// per-direction repacked weight block: 19 ct * 3 gates * 10 kt * 512 ushorts
#define WDIR 291840
// xg element layout: [dir][node][gate*304 + col], bf16
#define XGROW 912

typedef __attribute__((ext_vector_type(8))) short short8;
typedef __attribute__((ext_vector_type(4))) float f32x4;

__device__ __forceinline__ unsigned short f2bf(float f) {
  unsigned int u = __float_as_uint(f);
  u += 0x7FFFu + ((u >> 16) & 1u);
  return (unsigned short)(u >> 16);
}
__device__ __forceinline__ unsigned pack2bf(float a, float b) {
  return (unsigned)f2bf(a) | ((unsigned)f2bf(b) << 16);
}
__device__ __forceinline__ float bf2f(unsigned short u) {
  return __uint_as_float(((unsigned)u) << 16);
}

// ---------- segment start/len ----------
__global__ void seg_kernel(const int* __restrict__ batch, const int* __restrict__ pos,
                           int* __restrict__ seg_start, int* __restrict__ seg_len) {
  int i = blockIdx.x * blockDim.x + threadIdx.x;
  if (i >= N_) return;
  int b = batch[i], p = pos[i];
  if (p == 0) seg_start[b] = i;
  if (i == N_ - 1 || batch[i + 1] != b) seg_len[b] = p + 1;
}

// ---------- h0 = segment max ----------
__global__ void h0_kernel(const float* __restrict__ node, const int* __restrict__ seg_start,
                          const int* __restrict__ seg_len, float* __restrict__ h0) {
  int g = blockIdx.x;
  int col = threadIdx.x;
  if (col >= H_) return;
  int s0 = seg_start[g], L = seg_len[g];
  const float* p = node + (size_t)s0 * H_ + col;
  float ma = p[0], mb = -3.4e38f, mc = -3.4e38f, md = -3.4e38f;
  int r = 1;
  for (; r + 3 < L; r += 4) {
    ma = fmaxf(ma, p[(size_t)r * H_]);
    mb = fmaxf(mb, p[(size_t)(r + 1) * H_]);
    mc = fmaxf(mc, p[(size_t)(r + 2) * H_]);
    md = fmaxf(md, p[(size_t)(r + 3) * H_]);
  }
  for (; r < L; ++r) ma = fmaxf(ma, p[(size_t)r * H_]);
  h0[g * H_ + col] = fmaxf(fmaxf(ma, mb), fmaxf(mc, md));
}

// ---------- repack ih and hh weights (K=320-pad) into B-fragment order ----------
// dst[((ct*3+g)*10+kt)*512 + lane*8 + i]; k = kt*32+(lane>>4)*8+i; col = ct*16+(lane&15)
__global__ void wpack_kernel(const float* __restrict__ s0, const float* __restrict__ s1,
                             const float* __restrict__ s2, const float* __restrict__ s3,
                             unsigned short* __restrict__ wib, unsigned short* __restrict__ whb) {
  int f = blockIdx.x * 256 + threadIdx.x;  // < 583680 (= 2*WDIR per matrix pair? no: per matrix WDIR)
  if (f >= WDIR) return;
  int mat = blockIdx.y;  // 0:ih_f 1:ih_b 2:hh_f 3:hh_b
  const float* src = mat == 0 ? s0 : mat == 1 ? s1 : mat == 2 ? s2 : s3;
  unsigned short* dst = (mat < 2 ? wib : whb) + (size_t)(mat & 1) * WDIR;
  int i = f & 7, lane = (f >> 3) & 63, r = f >> 9;
  int kt = r % 10; r /= 10;
  int g = r % 3;  r /= 3;
  int ct = r;
  int k = kt * 32 + ((lane >> 4) << 3) + i;
  int col = ct * 16 + (lane & 15);
  float v = 0.f;
  if (col < 300 && k < 300) v = src[(g * 300 + col) * 300 + k];
  dst[f] = f2bf(v);
}

// ---------- xg = relu(node+bias) @ W_ih^T, all nodes, both dirs, bf16 out ----------
__global__ __launch_bounds__(256) void xg_kernel(const float* __restrict__ node,
                                                 const float* __restrict__ biasv,
                                                 const unsigned short* __restrict__ wib,
                                                 unsigned short* __restrict__ xg) {
  __shared__ unsigned short AS[64 * XSTR];
  int tid = threadIdx.x, mb = blockIdx.x, dir = blockIdx.y;
  int row0 = mb * 64;
  for (int idx = tid; idx < 64 * 82; idx += 256) {
    int rr = idx / 82, c4 = idx - rr * 82;
    uint2 pk = {0u, 0u};
    if (c4 < 75) {
      float4 v = *(const float4*)(node + (size_t)(row0 + rr) * 300 + c4 * 4);
      float4 bv = *(const float4*)(biasv + c4 * 4);
      pk.x = pack2bf(fmaxf(v.x + bv.x, 0.f), fmaxf(v.y + bv.y, 0.f));
      pk.y = pack2bf(fmaxf(v.z + bv.z, 0.f), fmaxf(v.w + bv.w, 0.f));
    }
    *(uint2*)&AS[rr * XSTR + c4 * 4] = pk;
  }
  __syncthreads();
  int lane = tid & 63, wave = tid >> 6;
  const unsigned short* wb = wib + (size_t)dir * WDIR;
  int arow = (lane & 15) * XSTR + ((lane >> 4) << 3);
  for (int ct = wave; ct < 19; ct += 4) {
    f32x4 acc[3][4] = {};
    const unsigned short* wt = wb + ct * (3 * 10 * 512) + lane * 8;
    #pragma unroll
    for (int kt = 0; kt < 10; ++kt) {
      short8 b0 = *(const short8*)(wt + kt * 512);
      short8 b1 = *(const short8*)(wt + (10 + kt) * 512);
      short8 b2 = *(const short8*)(wt + (20 + kt) * 512);
      #pragma unroll
      for (int m = 0; m < 4; ++m) {
        short8 a = *(const short8*)&AS[m * 16 * XSTR + arow + kt * 32];
        acc[0][m] = __builtin_amdgcn_mfma_f32_16x16x32_bf16(a, b0, acc[0][m], 0, 0, 0);
        acc[1][m] = __builtin_amdgcn_mfma_f32_16x16x32_bf16(a, b1, acc[1][m], 0, 0, 0);
        acc[2][m] = __builtin_amdgcn_mfma_f32_16x16x32_bf16(a, b2, acc[2][m], 0, 0, 0);
      }
    }
    int col = ct * 16 + (lane & 15);
    if (col < 300) {
      int rl0 = (lane >> 4) * 4;
      #pragma unroll
      for (int g = 0; g < 3; ++g)
        #pragma unroll
        for (int m = 0; m < 4; ++m)
          #pragma unroll
          for (int i = 0; i < 4; ++i) {
            int row = row0 + m * 16 + rl0 + i;
            xg[((size_t)dir * N_ + row) * XGROW + g * 304 + col] = f2bf(acc[g][m][i]);
          }
    }
  }
}

// ---------- recurrence: h_t = GRU(h_{t-1}, xg_t), hh-GEMM only ----------
// 128 blocks x 512 thr (8 waves). Block = 16 seqs of one direction.
// Wave w: col-tiles {w, w+8(, w+16 if w<3)}. Tile0 r,z weights register-resident;
// everything else streamed from L2 via 2x5-fragment ping-pong.
__global__ __launch_bounds__(512, 2) void gru2_kernel(
    const unsigned short* __restrict__ whb, const unsigned short* __restrict__ xg,
    const float* __restrict__ h0,
    const float* __restrict__ b_ih_f, const float* __restrict__ b_hh_f,
    const float* __restrict__ b_ih_b, const float* __restrict__ b_hh_b,
    const int* __restrict__ seg_start, const int* __restrict__ seg_len,
    float* __restrict__ out) {
  __shared__ unsigned short HBF[2][16 * XSTR];
  __shared__ float HS[16 * HSTR];
  __shared__ float BCr[304], BCz[304], BCni[304], BCnh[304];
  __shared__ int SST[16], SLN[16];

  int tid = threadIdx.x, blk = blockIdx.x;
  int dir = blk >> 6, db = blk & 63;

  if (tid < 16) {
    int g = (db < 32) ? 2 * (db * 16 + tid) : 2 * ((db - 32) * 16 + tid) + 1;
    SST[tid] = seg_start[g];
    SLN[tid] = seg_len[g];
  }
  const float* bi = dir ? b_ih_b : b_ih_f;
  const float* bh = dir ? b_hh_b : b_hh_f;
  for (int i = tid; i < 304; i += 512) {
    bool v = i < 300;
    BCr[i] = v ? bi[i] + bh[i] : 0.f;
    BCz[i] = v ? bi[300 + i] + bh[300 + i] : 0.f;
    BCni[i] = v ? bi[600 + i] : 0.f;
    BCnh[i] = v ? bh[600 + i] : 0.f;
  }
  // init h state
  for (int idx = tid; idx < 16 * 82; idx += 512) {
    int s = idx / 82, c4 = idx - s * 82;
    int g = (db < 32) ? 2 * (db * 16 + s) : 2 * ((db - 32) * 16 + s) + 1;
    float4 v = {0.f, 0.f, 0.f, 0.f};
    if (c4 < 75) v = *(const float4*)(h0 + (size_t)g * 300 + c4 * 4);
    if (c4 < 76) *(float4*)&HS[s * HSTR + c4 * 4] = v;
    uint2 pk;
    pk.x = pack2bf(v.x, v.y);
    pk.y = pack2bf(v.z, v.w);
    *(uint2*)&HBF[0][s * XSTR + c4 * 4] = pk;
    uint2 z = {0u, 0u};
    *(uint2*)&HBF[1][s * XSTR + c4 * 4] = z;
  }
  __syncthreads();

  int nsteps = 64;
  if (dir == 0) {
    int m = 0;
    for (int s = 0; s < 16; ++s) m = max(m, SLN[s]);
    nsteps = m;
  }

  int lane = tid & 63, wave = tid >> 6;
  int ntile = (wave < 3) ? 3 : 2;
  const unsigned short* wbase = whb + (size_t)dir * WDIR + lane * 8;
  // W(ct,g,kt) fragment at wbase + ((ct*3+g)*10+kt)*512

  // register-resident r,z of tile0 (ct = wave)
  short8 WRZ[20];
  #pragma unroll
  for (int j = 0; j < 20; ++j)
    WRZ[j] = *(const short8*)(wbase + ((wave * 3 + (j >= 10 ? 1 : 0)) * 10 + (j % 10)) * 512);

  int arow = (lane & 15) * XSTR + ((lane >> 4) << 3);
  int lcol = lane & 15;
  int s0w = (lane >> 4) * 4;
  const unsigned short* xgd = xg + (size_t)dir * N_ * XGROW;

  for (int t = 0; t < nsteps; ++t) {
    int tt = dir ? 63 - t : t;
    int rb = t & 1, wbuf = rb ^ 1;
    const unsigned short* hb = &HBF[rb][0];

    short8 AH[10];
    #pragma unroll
    for (int kt = 0; kt < 10; ++kt) AH[kt] = *(const short8*)&hb[arow + kt * 32];

    // ---------------- tile 0: reg r,z + streamed n ----------------
    {
      int ct = wave;
      int col = ct * 16 + lcol;
      bool cv = col < 300;
      const unsigned short* wn = wbase + ((ct * 3 + 2) * 10) * 512;
      short8 S0[5], S1[5];
      #pragma unroll
      for (int j = 0; j < 5; ++j) S0[j] = *(const short8*)(wn + j * 512);
      #pragma unroll
      for (int j = 0; j < 5; ++j) S1[j] = *(const short8*)(wn + (5 + j) * 512);

      float xr[4], xz[4], xn[4];
      #pragma unroll
      for (int i = 0; i < 4; ++i) {
        int s = s0w + i;
        bool v = cv && (tt < SLN[s]);
        const unsigned short* xp = xgd + (size_t)(SST[s] + tt) * XGROW + col;
        xr[i] = v ? bf2f(xp[0]) : 0.f;
        xz[i] = v ? bf2f(xp[304]) : 0.f;
        xn[i] = v ? bf2f(xp[608]) : 0.f;
      }

      f32x4 ar = {0, 0, 0, 0}, az = {0, 0, 0, 0}, an = {0, 0, 0, 0};
      #pragma unroll
      for (int kt = 0; kt < 10; ++kt) {
        ar = __builtin_amdgcn_mfma_f32_16x16x32_bf16(AH[kt], WRZ[kt], ar, 0, 0, 0);
        az = __builtin_amdgcn_mfma_f32_16x16x32_bf16(AH[kt], WRZ[10 + kt], az, 0, 0, 0);
      }
      #pragma unroll
      for (int kt = 0; kt < 5; ++kt)
        an = __builtin_amdgcn_mfma_f32_16x16x32_bf16(AH[kt], S0[kt], an, 0, 0, 0);
      #pragma unroll
      for (int kt = 0; kt < 5; ++kt)
        an = __builtin_amdgcn_mfma_f32_16x16x32_bf16(AH[5 + kt], S1[kt], an, 0, 0, 0);

      #pragma unroll
      for (int i = 0; i < 4; ++i) {
        int s = s0w + i;
        float pr = ar[i] + xr[i] + BCr[col];
        float pz = az[i] + xz[i] + BCz[col];
        float rr = 1.f / (1.f + __expf(-pr));
        float zz = 1.f / (1.f + __expf(-pz));
        float pn = (xn[i] + BCni[col]) + rr * (an[i] + BCnh[col]);
        float nn = 1.f - 2.f / (__expf(2.f * pn) + 1.f);
        float ho = HS[s * HSTR + col];
        float hn = fmaf(zz, ho - nn, nn);
        HS[s * HSTR + col] = hn;
        HBF[wbuf][s * XSTR + col] = f2bf(hn);
        if (cv && tt < SLN[s]) out[(size_t)(SST[s] + tt) * 600 + dir * 300 + col] = hn;
      }
    }

    // ---------------- streamed tiles ----------------
    for (int ti = 1; ti < ntile; ++ti) {
      int ct = wave + ti * 8;
      int col = ct * 16 + lcol;
      bool cv = col < 300;
      const unsigned short* wt = wbase + (ct * 3 * 10) * 512;
      short8 T0[5], T1[5];
      #pragma unroll
      for (int j = 0; j < 5; ++j) T0[j] = *(const short8*)(wt + j * 512);        // r lo
      #pragma unroll
      for (int j = 0; j < 5; ++j) T1[j] = *(const short8*)(wt + (5 + j) * 512);  // r hi

      float xr[4], xz[4], xn[4];
      #pragma unroll
      for (int i = 0; i < 4; ++i) {
        int s = s0w + i;
        bool v = cv && (tt < SLN[s]);
        const unsigned short* xp = xgd + (size_t)(SST[s] + tt) * XGROW + col;
        xr[i] = v ? bf2f(xp[0]) : 0.f;
        xz[i] = v ? bf2f(xp[304]) : 0.f;
        xn[i] = v ? bf2f(xp[608]) : 0.f;
      }

      f32x4 ar = {0, 0, 0, 0}, az = {0, 0, 0, 0}, an = {0, 0, 0, 0};
      #pragma unroll
      for (int kt = 0; kt < 5; ++kt)
        ar = __builtin_amdgcn_mfma_f32_16x16x32_bf16(AH[kt], T0[kt], ar, 0, 0, 0);
      #pragma unroll
      for (int j = 0; j < 5; ++j) T0[j] = *(const short8*)(wt + (10 + j) * 512);  // z lo
      #pragma unroll
      for (int kt = 0; kt < 5; ++kt)
        ar = __builtin_amdgcn_mfma_f32_16x16x32_bf16(AH[5 + kt], T1[kt], ar, 0, 0, 0);
      #pragma unroll
      for (int j = 0; j < 5; ++j) T1[j] = *(const short8*)(wt + (15 + j) * 512);  // z hi
      #pragma unroll
      for (int kt = 0; kt < 5; ++kt)
        az = __builtin_amdgcn_mfma_f32_16x16x32_bf16(AH[kt], T0[kt], az, 0, 0, 0);
      #pragma unroll
      for (int j = 0; j < 5; ++j) T0[j] = *(const short8*)(wt + (20 + j) * 512);  // n lo
      #pragma unroll
      for (int kt = 0; kt < 5; ++kt)
        az = __builtin_amdgcn_mfma_f32_16x16x32_bf16(AH[5 + kt], T1[kt], az, 0, 0, 0);
      #pragma unroll
      for (int j = 0; j < 5; ++j) T1[j] = *(const short8*)(wt + (25 + j) * 512);  // n hi
      #pragma unroll
      for (int kt = 0; kt < 5; ++kt)
        an = __builtin_amdgcn_mfma_f32_16x16x32_bf16(AH[kt], T0[kt], an, 0, 0, 0);
      #pragma unroll
      for (int kt = 0; kt < 5; ++kt)
        an = __builtin_amdgcn_mfma_f32_16x16x32_bf16(AH[5 + kt], T1[kt], an, 0, 0, 0);

      #pragma unroll
      for (int i = 0; i < 4; ++i) {
        int s = s0w + i;
        float pr = ar[i] + xr[i] + BCr[col];
        float pz = az[i] + xz[i] + BCz[col];
        float rr = 1.f / (1.f + __expf(-pr));
        float zz = 1.f / (1.f + __expf(-pz));
        float pn = (xn[i] + BCni[col]) + rr * (an[i] + BCnh[col]);
        float nn = 1.f - 2.f / (__expf(2.f * pn) + 1.f);
        float ho = HS[s * HSTR + col];
        float hn = fmaf(zz, ho - nn, nn);
        HS[s * HSTR + col] = hn;
        HBF[wbuf][s * XSTR + col] = f2bf(hn);
        if (cv && tt < SLN[s]) out[(size_t)(SST[s] + tt) * 600 + dir * 300 + col] = hn;
      }
    }
    __syncthreads();
  }
}

// ================= fallback (round-2, known-pass) for small ws =================
#define GST (19 * 20 * 512)
#define FXSTR 344

__global__ void wb_kernel(const float* __restrict__ w_ih_f, const float* __restrict__ w_hh_f,
                          const float* __restrict__ w_ih_b, const float* __restrict__ w_hh_b,
                          unsigned short* __restrict__ wb) {
  int f = blockIdx.x * blockDim.x + threadIdx.x;
  int i = f & 7;
  int l = (f >> 3) & 63;
  int rest = f >> 9;
  int kt = rest % 20; rest /= 20;
  int ct = rest % 19; rest /= 19;
  int gate = rest % 3;
  int dir = rest / 3;
  int kg = kt * 32 + ((l >> 4) << 3) + i;
  int col = ct * 16 + (l & 15);
  float v = 0.f;
  if (col < 300) {
    int j = gate * 300 + col;
    if (kg < 320) {
      if (kg < 300) v = (dir ? w_ih_b : w_ih_f)[j * 300 + kg];
    } else {
      int k2 = kg - 320;
      if (k2 < 300) v = (dir ? w_hh_b : w_hh_f)[j * 300 + k2];
    }
  }
  wb[f] = f2bf(v);
}

__global__ __launch_bounds__(1024) void gru_fb_kernel(
    const float* __restrict__ node, const float* __restrict__ biasv,
    const float* __restrict__ b_ih_f, const float* __restrict__ b_hh_f,
    const float* __restrict__ b_ih_b, const float* __restrict__ b_hh_b,
    const unsigned short* __restrict__ wb, const float* __restrict__ h0,
    const int* __restrict__ seg_start, const int* __restrict__ seg_len,
    float* __restrict__ out) {
  __shared__ unsigned short XS[32 * FXSTR];
  __shared__ unsigned short HBF[2][32 * FXSTR];
  __shared__ float HS[32 * 304];
  __shared__ float BI[912], BH[912], BB[304];
  __shared__ int SST[32], SLN[32], SGG[32];

  int tid = threadIdx.x;
  int blk = blockIdx.x;
  int dir = blk >> 5;
  int db = blk & 31;

  if (tid < 32) {
    int s = tid;
    int g = (db < 16) ? 2 * (db * 32 + s) : 2 * ((db - 16) * 32 + s) + 1;
    SGG[s] = g;
    SST[s] = seg_start[g];
    SLN[s] = seg_len[g];
  }
  const float* bip = dir ? b_ih_b : b_ih_f;
  const float* bhp = dir ? b_hh_b : b_hh_f;
  for (int idx = tid; idx < 912; idx += 1024) {
    BI[idx] = idx < 900 ? bip[idx] : 0.f;
    BH[idx] = idx < 900 ? bhp[idx] : 0.f;
  }
  for (int idx = tid; idx < 75; idx += 1024)
    *(float4*)&BB[idx * 4] = *(const float4*)&biasv[idx * 4];
  __syncthreads();

  for (int idx = tid; idx < 32 * 86; idx += 1024) {
    int s = idx / 86, c4 = idx - s * 86;
    float4 v = {0.f, 0.f, 0.f, 0.f};
    if (c4 < 75) v = *(const float4*)(h0 + (size_t)SGG[s] * 300 + c4 * 4);
    if (c4 < 76) *(float4*)&HS[s * 304 + c4 * 4] = v;
    uint2 pk;
    pk.x = pack2bf(v.x, v.y);
    pk.y = pack2bf(v.z, v.w);
    *(uint2*)&HBF[0][s * FXSTR + c4 * 4] = pk;
    uint2 z2 = {0u, 0u};
    *(uint2*)&HBF[1][s * FXSTR + c4 * 4] = z2;
    *(uint2*)&XS[s * FXSTR + c4 * 4] = z2;
  }

  int nsteps = 64;
  if (dir == 0) {
    int m = 0;
    for (int s = 0; s < 32; ++s) m = max(m, SLN[s]);
    nsteps = m;
  }

  int lane = tid & 63;
  int wave = tid >> 6;
  const unsigned short* wbd = wb + (size_t)dir * 3 * GST;
  int arow0 = (lane & 15) * FXSTR + ((lane >> 4) << 3);

  for (int t = 0; t < nsteps; ++t) {
    int tt = dir ? (63 - t) : t;
    int rb = t & 1, wbuf = rb ^ 1;

    for (int idx = tid; idx < 32 * 84; idx += 1024) {
      int s = idx / 84, c4 = idx - s * 84;
      uint2 pk = {0u, 0u};
      if (c4 < 75 && tt < SLN[s]) {
        float4 v = *(const float4*)(node + (size_t)(SST[s] + tt) * 300 + c4 * 4);
        float4 bv = *(const float4*)&BB[c4 * 4];
        pk.x = pack2bf(fmaxf(v.x + bv.x, 0.f), fmaxf(v.y + bv.y, 0.f));
        pk.y = pack2bf(fmaxf(v.z + bv.z, 0.f), fmaxf(v.w + bv.w, 0.f));
      }
      if (c4 < 84) *(uint2*)&XS[s * FXSTR + c4 * 4] = pk;
    }
    __syncthreads();

    for (int ct = wave; ct < 19; ct += 16) {
      f32x4 ar0 = {0,0,0,0}, ar1 = {0,0,0,0}, az0 = {0,0,0,0}, az1 = {0,0,0,0};
      f32x4 ani0 = {0,0,0,0}, ani1 = {0,0,0,0}, anh0 = {0,0,0,0}, anh1 = {0,0,0,0};
      const unsigned short* wct = wbd + ct * (20 * 512) + lane * 8;

      #pragma unroll
      for (int kt = 0; kt < 10; ++kt) {
        short8 a0 = *(const short8*)&XS[arow0 + kt * 32];
        short8 a1 = *(const short8*)&XS[arow0 + 16 * FXSTR + kt * 32];
        short8 br = *(const short8*)(wct + kt * 512);
        short8 bz = *(const short8*)(wct + GST + kt * 512);
        short8 bn = *(const short8*)(wct + 2 * GST + kt * 512);
        ar0 = __builtin_amdgcn_mfma_f32_16x16x32_bf16(a0, br, ar0, 0, 0, 0);
        ar1 = __builtin_amdgcn_mfma_f32_16x16x32_bf16(a1, br, ar1, 0, 0, 0);
        az0 = __builtin_amdgcn_mfma_f32_16x16x32_bf16(a0, bz, az0, 0, 0, 0);
        az1 = __builtin_amdgcn_mfma_f32_16x16x32_bf16(a1, bz, az1, 0, 0, 0);
        ani0 = __builtin_amdgcn_mfma_f32_16x16x32_bf16(a0, bn, ani0, 0, 0, 0);
        ani1 = __builtin_amdgcn_mfma_f32_16x16x32_bf16(a1, bn, ani1, 0, 0, 0);
      }
      const unsigned short* hb = &HBF[rb][0];
      #pragma unroll
      for (int kt = 0; kt < 10; ++kt) {
        short8 a0 = *(const short8*)&hb[arow0 + kt * 32];
        short8 a1 = *(const short8*)&hb[arow0 + 16 * FXSTR + kt * 32];
        short8 br = *(const short8*)(wct + (10 + kt) * 512);
        short8 bz = *(const short8*)(wct + GST + (10 + kt) * 512);
        short8 bn = *(const short8*)(wct + 2 * GST + (10 + kt) * 512);
        ar0 = __builtin_amdgcn_mfma_f32_16x16x32_bf16(a0, br, ar0, 0, 0, 0);
        ar1 = __builtin_amdgcn_mfma_f32_16x16x32_bf16(a1, br, ar1, 0, 0, 0);
        az0 = __builtin_amdgcn_mfma_f32_16x16x32_bf16(a0, bz, az0, 0, 0, 0);
        az1 = __builtin_amdgcn_mfma_f32_16x16x32_bf16(a1, bz, az1, 0, 0, 0);
        anh0 = __builtin_amdgcn_mfma_f32_16x16x32_bf16(a0, bn, anh0, 0, 0, 0);
        anh1 = __builtin_amdgcn_mfma_f32_16x16x32_bf16(a1, bn, anh1, 0, 0, 0);
      }

      int col = ct * 16 + (lane & 15);
      float bir = BI[col] + BH[col];
      float biz = BI[300 + col] + BH[300 + col];
      float bin = BI[600 + col];
      float bhn = BH[600 + col];
      int r0 = (lane >> 4) << 2;
      #pragma unroll
      for (int mt = 0; mt < 2; ++mt) {
        f32x4 ar = mt ? ar1 : ar0;
        f32x4 az = mt ? az1 : az0;
        f32x4 ani = mt ? ani1 : ani0;
        f32x4 anh = mt ? anh1 : anh0;
        #pragma unroll
        for (int i = 0; i < 4; ++i) {
          int s = mt * 16 + r0 + i;
          float pr = ar[i] + bir;
          float pz = az[i] + biz;
          float rr = 1.f / (1.f + __expf(-pr));
          float zz = 1.f / (1.f + __expf(-pz));
          float pn = (ani[i] + bin) + rr * (anh[i] + bhn);
          float nn = 1.f - 2.f / (__expf(2.f * pn) + 1.f);
          float ho = HS[s * 304 + col];
          float hn = fmaf(zz, ho - nn, nn);
          HS[s * 304 + col] = hn;
          HBF[wbuf][s * FXSTR + col] = f2bf(hn);
          if (col < 300 && tt < SLN[s])
            out[(size_t)(SST[s] + tt) * 600 + dir * 300 + col] = hn;
        }
      }
    }
    __syncthreads();
  }
}

extern "C" void kernel_launch(void* const* d_in, const int* in_sizes, int n_in,
                              void* d_out, int out_size, void* d_ws, size_t ws_size,
                              hipStream_t stream) {
  const float* node   = (const float*)d_in[0];
  const int*   batch  = (const int*)d_in[1];
  const int*   pos    = (const int*)d_in[2];
  const float* bias   = (const float*)d_in[3];
  const float* w_ih_f = (const float*)d_in[4];
  const float* w_hh_f = (const float*)d_in[5];
  const float* b_ih_f = (const float*)d_in[6];
  const float* b_hh_f = (const float*)d_in[7];
  const float* w_ih_b = (const float*)d_in[8];
  const float* w_hh_b = (const float*)d_in[9];
  const float* b_ih_b = (const float*)d_in[10];
  const float* b_hh_b = (const float*)d_in[11];
  float* outp = (float*)d_out;

  // ws layout: whb | wib | h0 | seg_start | seg_len | xg
  size_t off_whb = 0;
  size_t off_wib = off_whb + (size_t)2 * WDIR * 2;          // 1,167,360
  size_t off_h0  = off_wib + (size_t)2 * WDIR * 2;          // 2,334,720
  size_t off_ss  = off_h0 + (size_t)B_ * H_ * 4;            // 3,563,520
  size_t off_sl  = off_ss + 4096;
  size_t off_xg  = off_sl + 4096;
  size_t need    = off_xg + (size_t)2 * N_ * XGROW * 2;     // ~182.9 MB

  unsigned short* whb = (unsigned short*)((char*)d_ws + off_whb);
  unsigned short* wib = (unsigned short*)((char*)d_ws + off_wib);
  float* h0 = (float*)((char*)d_ws + off_h0);
  int* seg_start = (int*)((char*)d_ws + off_ss);
  int* seg_len = (int*)((char*)d_ws + off_sl);
  unsigned short* xg = (unsigned short*)((char*)d_ws + off_xg);

  seg_kernel<<<(N_ + 255) / 256, 256, 0, stream>>>(batch, pos, seg_start, seg_len);
  h0_kernel<<<B_, 320, 0, stream>>>(node, seg_start, seg_len, h0);

  if (ws_size >= need) {
    wpack_kernel<<<dim3((WDIR + 255) / 256, 4), 256, 0, stream>>>(
        w_ih_f, w_ih_b, w_hh_f, w_hh_b, wib, whb);
    xg_kernel<<<dim3(N_ / 64, 2), 256, 0, stream>>>(node, bias, wib, xg);
    gru2_kernel<<<128, 512, 0, stream>>>(whb, xg, h0, b_ih_f, b_hh_f, b_ih_b, b_hh_b,
                                         seg_start, seg_len, outp);
  } else {
    unsigned short* wb = (unsigned short*)d_ws;  // reuse whb+wib region (same size)
    wb_kernel<<<4560, 256, 0, stream>>>(w_ih_f, w_hh_f, w_ih_b, w_hh_b, wb);
    gru_fb_kernel<<<64, 1024, 0, stream>>>(node, bias, b_ih_f, b_hh_f, b_ih_b, b_hh_b,
                                           wb, h0, seg_start, seg_len, outp);
  }
}